// Round 3
// baseline (324.079 us; speedup 1.0000x reference)
//
#include <hip/hip_runtime.h>
#include <cmath>

// Shapes: B=4, V=8, D=64, N=16, H=32, W=32, GROUPS=4
// rotation tables: a = radians(-45*v); c = cos(a), s = sin(a)
#define FSQ 0.70710678118654752440f
__constant__ float CTAB[8] = {1.f,  FSQ, 0.f, -FSQ, -1.f, -FSQ, 0.f, FSQ};
__constant__ float STAB[8] = {0.f, -FSQ, -1.f, -FSQ,  0.f,  FSQ, 1.f, FSQ};

// ---------------------------------------------------------------------------
// GroupNorm: 16 blocks = (b, group). Writes u_norm into zero-padded (34x34)
// planes in ws (border zeros == conv SAME padding).
// ---------------------------------------------------------------------------
__global__ __launch_bounds__(256) void gn_kernel(const float* __restrict__ u,
                                                 const float* __restrict__ gw,
                                                 const float* __restrict__ gb,
                                                 float* __restrict__ up)
{
    int blk = blockIdx.x;            // b*4 + g
    int b = blk >> 2, g = blk & 3;
    int t = threadIdx.x;
    const float* src = u + ((size_t)(b * 64 + g * 16) << 10);   // 16384 floats
    float sum = 0.f, sq = 0.f;
    #pragma unroll
    for (int r = 0; r < 64; ++r) {
        float v = src[t + (r << 8)];
        sum += v; sq += v * v;
    }
    __shared__ float red[256], red2[256];
    red[t] = sum; red2[t] = sq;
    __syncthreads();
    for (int ofs = 128; ofs > 0; ofs >>= 1) {
        if (t < ofs) { red[t] += red[t + ofs]; red2[t] += red2[t + ofs]; }
        __syncthreads();
    }
    float mu  = red[0] * (1.f / 16384.f);
    float var = red2[0] * (1.f / 16384.f) - mu * mu;
    float rs  = rsqrtf(var + 1e-5f);

    float* pb = up + (size_t)(b * 64 + g * 16) * 1156;
    for (int k = t; k < 16 * 132; k += 256) {
        int pl = k / 132, c = k % 132;
        int idx;
        if (c < 34)       idx = c;                       // row 0
        else if (c < 68)  idx = 33 * 34 + (c - 34);      // row 33
        else if (c < 100) idx = (c - 68 + 1) * 34;       // col 0, rows 1..32
        else              idx = (c - 100 + 1) * 34 + 33; // col 33, rows 1..32
        pb[pl * 1156 + idx] = 0.f;
    }
    for (int r = 0; r < 64; ++r) {
        int idx = t + (r << 8);
        int ch = idx >> 10, rem = idx & 1023;
        int y = rem >> 5, x = rem & 31;
        float val = (src[idx] - mu) * rs * gw[g * 16 + ch] + gb[g * 16 + ch];
        pb[ch * 1156 + (y + 1) * 34 + (x + 1)] = val;
    }
}

// ---------------------------------------------------------------------------
// 3x3 SAME convs, LDS-staged: 3072 blocks = (b, o, strip).
// ---------------------------------------------------------------------------
__global__ __launch_bounds__(256) void conv_kernel(const float* __restrict__ up,
                                                   const float* __restrict__ wd,
                                                   const float* __restrict__ bd,
                                                   const float* __restrict__ wB,
                                                   const float* __restrict__ wC,
                                                   const float* __restrict__ dtb,
                                                   float* __restrict__ delta,
                                                   float* __restrict__ Bv,
                                                   float* __restrict__ Cv)
{
    __shared__ float sin_[64 * 204];   // 64 ci x 6 rows x 34 cols
    __shared__ float red[256];
    int blk = blockIdx.x;              // b*768 + o*8 + strip
    int strip = blk & 7;
    int b = blk / 768;
    int o = (blk >> 3) - b * 96;
    int h0 = strip * 4;
    int t = threadIdx.x;

    const float* plane = up + (size_t)b * 73984;   // 64*1156
    for (int idx = t; idx < 13056; idx += 256) {
        int ci = idx / 204;
        int rem = idx - ci * 204;
        sin_[idx] = plane[ci * 1156 + h0 * 34 + rem];
    }
    __syncthreads();

    const float* wsel;
    if (o < 64)      wsel = wd + (size_t)o * 576;
    else if (o < 80) wsel = wB + (size_t)(o - 64) * 576;
    else             wsel = wC + (size_t)(o - 80) * 576;

    int half = t >> 7;
    int px = t & 127;
    int r = px >> 5, c = px & 31;
    const float* base = sin_ + r * 34 + c;

    float acc = 0.f;
    int ci0 = half * 32;
    for (int ci = ci0; ci < ci0 + 32; ++ci) {
        const float* pp = base + ci * 204;
        const float* wp = wsel + ci * 9;
        #pragma unroll
        for (int dy = 0; dy < 3; ++dy)
            #pragma unroll
            for (int dx = 0; dx < 3; ++dx)
                acc += pp[dy * 34 + dx] * wp[dy * 3 + dx];
    }
    red[t] = acc;
    __syncthreads();
    if (t < 128) {
        float a = red[t] + red[t + 128];
        int pidx = (h0 + r) * 32 + c;
        if (o < 64) {
            float x = a + bd[o] + dtb[0];
            float sp = (x > 20.f) ? x : log1pf(expf(x));
            sp = fminf(fmaxf(sp, 1e-4f), 5.f);
            delta[((size_t)(b * 64 + o) << 10) + pidx] = sp;
        } else if (o < 80) {
            Bv[((size_t)(b * 16 + o - 64) << 10) + pidx] = a;
        } else {
            Cv[((size_t)(b * 16 + o - 80) << 10) + pidx] = a;
        }
    }
}

// ---------------------------------------------------------------------------
// Main fused kernel: 2048 blocks = (b, v, d). Thread owns 4 consecutive x
// pixels (float4 loads/stores on delta/u/Bv/Cv/s_out/y).
// v-class specialization (fp32 rotation coeffs make even-v grids exactly
// integer):
//   v=0: identity, v=4: 180-flip  -> pure streaming, no LDS
//   v=2,6: transpose-flips        -> LDS, 1 tap (conflict-free: 2 lanes/bank)
//   v odd: true bilinear, 4 taps  -> LDS + zero guard border
// LDS: 8 planes/chunk, stride-34 rows; staging scalar b32 (conflict-free).
// y written once per block (no atomics, no memset).
// ---------------------------------------------------------------------------
__global__ __launch_bounds__(256) void fused_state_kernel(
    const float* __restrict__ s_prev, const float* __restrict__ u_t,
    const float* __restrict__ delta, const float* __restrict__ Bv,
    const float* __restrict__ Cv, const float* __restrict__ logA,
    const float* __restrict__ Dp, float* __restrict__ y_out,
    float* __restrict__ s_out)
{
    __shared__ float lds[8 * 1156];   // 36992 B
    __shared__ float Ash[16];
    int blk = blockIdx.x;
    int d = blk & 63, v = (blk >> 6) & 7, b = blk >> 9;
    int t = threadIdx.x;

    int h = t >> 3;            // row 0..31
    int x = (t & 7) << 2;      // col base 0,4,...,28 (4 px per thread)

    if (t < 16) Ash[t] = -__expf(logA[d * 16 + t]);

    bool is_odd = (v & 1);
    if (is_odd) {
        // zero guard cells (8 planes x 132 border cells)
        for (int k = t; k < 1056; k += 256) {
            int pl = k / 132, g = k - pl * 132;
            int idx;
            if (g < 34)       idx = g;
            else if (g < 68)  idx = 1122 + (g - 34);
            else if (g < 100) idx = (g - 67) * 34;
            else              idx = (g - 99) * 34 + 33;
            lds[pl * 1156 + idx] = 0.f;
        }
    }
    __syncthreads();   // Ash + guard visible to all

    size_t so = ((size_t)((b * 8 + v) * 64 + d)) << 14;   // *16384
    const float*  sb   = s_prev + so;
    float*        sob  = s_out + so;
    const float4* dpl4 = (const float4*)(delta + ((size_t)(b * 64 + d) << 10));
    const float4* upl4 = (const float4*)(u_t   + ((size_t)(b * 64 + d) << 10));
    const float4* Bv4  = (const float4*)(Bv + ((size_t)b << 14));
    const float4* Cv4  = (const float4*)(Cv + ((size_t)b << 14));
    float4*       sot4 = (float4*)sob;
    float4*       yo4  = (float4*)(y_out + (((size_t)((b * 8 + v) * 64 + d)) << 10));

    float4 dl = dpl4[t];
    float4 uu = upl4[t];
    float4 du = make_float4(dl.x * uu.x, dl.y * uu.y, dl.z * uu.z, dl.w * uu.w);
    float4 yacc = make_float4(0.f, 0.f, 0.f, 0.f);

    if (v == 0 || v == 4) {
        // ---- streaming path: no LDS ----
        const float4* sp4 = (const float4*)sb;
        int rd = (v == 0) ? t : (((31 - h) << 3) + ((28 - x) >> 2));
        #pragma unroll
        for (int nn = 0; nn < 16; ++nn) {
            float4 sp = sp4[(nn << 8) + rd];
            float s0, s1, s2, s3;
            if (v == 0) { s0 = sp.x; s1 = sp.y; s2 = sp.z; s3 = sp.w; }
            else        { s0 = sp.w; s1 = sp.z; s2 = sp.y; s3 = sp.x; }
            float A = Ash[nn];
            float4 bv = Bv4[(nn << 8) + t];
            float4 cv = Cv4[(nn << 8) + t];
            float4 sn;
            sn.x = __expf(dl.x * A) * s0 + du.x * bv.x;
            sn.y = __expf(dl.y * A) * s1 + du.y * bv.y;
            sn.z = __expf(dl.z * A) * s2 + du.z * bv.z;
            sn.w = __expf(dl.w * A) * s3 + du.w * bv.w;
            sot4[(nn << 8) + t] = sn;
            yacc.x += sn.x * cv.x; yacc.y += sn.y * cv.y;
            yacc.z += sn.z * cv.z; yacc.w += sn.w * cv.w;
        }
    } else {
        // precompute per-pixel LDS tap info
        int base0[4];
        float w00[4], w01[4], w10[4], w11[4];
        if (is_odd) {
            const float cc = CTAB[v], ss = STAB[v];
            #pragma unroll
            for (int j = 0; j < 4; ++j) {
                float X = (x + j + 0.5f) * 0.0625f - 1.f;
                float Y = (h + 0.5f) * 0.0625f - 1.f;
                float gx = cc * X - ss * Y;
                float gy = ss * X + cc * Y;
                float ix = (gx + 1.f) * 16.f - 0.5f;
                float iy = (gy + 1.f) * 16.f - 0.5f;
                float fx0 = floorf(ix), fy0 = floorf(iy);
                float wx = ix - fx0, wy = iy - fy0;
                int x0 = (int)fx0, y0 = (int)fy0;
                float mx0 = (x0 >= 0 && x0 < 32) ? (1.f - wx) : 0.f;
                float mx1 = (x0 >= -1 && x0 < 31) ? wx : 0.f;
                float my0 = (y0 >= 0 && y0 < 32) ? (1.f - wy) : 0.f;
                float my1 = (y0 >= -1 && y0 < 31) ? wy : 0.f;
                w00[j] = my0 * mx0; w01[j] = my0 * mx1;
                w10[j] = my1 * mx0; w11[j] = my1 * mx1;
                int bx = min(max(x0, -1), 31), by = min(max(y0, -1), 31);
                base0[j] = (by + 1) * 34 + (bx + 1);
            }
        } else {
            // v==2: in(31-x-j, h)   v==6: in(x+j, 31-h)
            #pragma unroll
            for (int j = 0; j < 4; ++j) {
                if (v == 2) base0[j] = (32 - x - j) * 34 + (h + 1);
                else        base0[j] = (x + j + 1) * 34 + (32 - h);
            }
        }

        for (int ch = 0; ch < 2; ++ch) {
            // stage 8 planes, scalar b32: coalesced global, conflict-free LDS
            const float* src = sb + (ch << 13);
            #pragma unroll
            for (int k = 0; k < 32; ++k) {
                int idx = t + (k << 8);
                int nn = idx >> 10, rem = idx & 1023;
                lds[nn * 1156 + ((rem >> 5) + 1) * 34 + (rem & 31) + 1] = src[idx];
            }
            __syncthreads();

            #pragma unroll
            for (int n = 0; n < 8; ++n) {
                int nn = (ch << 3) + n;
                float A = Ash[nn];
                float4 bv = Bv4[(nn << 8) + t];
                float4 cv = Cv4[(nn << 8) + t];
                float bil[4];
                if (is_odd) {
                    #pragma unroll
                    for (int j = 0; j < 4; ++j) {
                        int si = base0[j] + n * 1156;
                        bil[j] = lds[si] * w00[j] + lds[si + 1] * w01[j]
                               + lds[si + 34] * w10[j] + lds[si + 35] * w11[j];
                    }
                } else {
                    #pragma unroll
                    for (int j = 0; j < 4; ++j)
                        bil[j] = lds[base0[j] + n * 1156];
                }
                float4 sn;
                sn.x = __expf(dl.x * A) * bil[0] + du.x * bv.x;
                sn.y = __expf(dl.y * A) * bil[1] + du.y * bv.y;
                sn.z = __expf(dl.z * A) * bil[2] + du.z * bv.z;
                sn.w = __expf(dl.w * A) * bil[3] + du.w * bv.w;
                sot4[(nn << 8) + t] = sn;
                yacc.x += sn.x * cv.x; yacc.y += sn.y * cv.y;
                yacc.z += sn.z * cv.z; yacc.w += sn.w * cv.w;
            }
            __syncthreads();
        }
    }

    float Dd = Dp[d];
    float4 y4;
    y4.x = yacc.x + uu.x * Dd;
    y4.y = yacc.y + uu.y * Dd;
    y4.z = yacc.z + uu.z * Dd;
    y4.w = yacc.w + uu.w * Dd;
    yo4[t] = y4;
}

// ---------------------------------------------------------------------------
extern "C" void kernel_launch(void* const* d_in, const int* in_sizes, int n_in,
                              void* d_out, int out_size, void* d_ws, size_t ws_size,
                              hipStream_t stream)
{
    const float* u_t    = (const float*)d_in[0];
    const float* s_prev = (const float*)d_in[1];
    const float* gn_w   = (const float*)d_in[2];
    const float* gn_b   = (const float*)d_in[3];
    const float* wd     = (const float*)d_in[4];
    const float* bd     = (const float*)d_in[5];
    const float* wB     = (const float*)d_in[6];
    const float* wC     = (const float*)d_in[7];
    const float* logA   = (const float*)d_in[8];
    const float* Dp     = (const float*)d_in[9];
    const float* dtb    = (const float*)d_in[10];

    float* y_out = (float*)d_out;            // (4,8,64,32,32) = 2097152 floats
    float* s_out = y_out + 2097152;          // (4,8,64,16,32,32) = 33554432 floats

    float* up    = (float*)d_ws;             // padded u_norm: 4*64*1156
    float* delta = up + 295936;              // 4*64*1024
    float* Bv    = delta + 262144;           // 4*16*1024
    float* Cv    = Bv + 65536;               // 4*16*1024

    hipLaunchKernelGGL(gn_kernel, dim3(16), dim3(256), 0, stream, u_t, gn_w, gn_b, up);
    hipLaunchKernelGGL(conv_kernel, dim3(3072), dim3(256), 0, stream,
                       up, wd, bd, wB, wC, dtb, delta, Bv, Cv);
    hipLaunchKernelGGL(fused_state_kernel, dim3(2048), dim3(256), 0, stream,
                       s_prev, u_t, delta, Bv, Cv, logA, Dp, y_out, s_out);
}